// Round 12
// baseline (402.473 us; speedup 1.0000x reference)
//
#include <hip/hip_runtime.h>
#include <math.h>

#define HW 36864
#define IMGW 192

typedef unsigned short u16;
typedef __attribute__((ext_vector_type(8))) short short8;
typedef __attribute__((ext_vector_type(8))) unsigned short ushort8;
typedef __attribute__((ext_vector_type(16))) float f32x16;

__device__ __forceinline__ float b2f(u16 u){ return __uint_as_float(((unsigned)u)<<16); }
__device__ __forceinline__ u16 f2b(float f){
    unsigned u = __float_as_uint(f);
    return (u16)((u + 0x7FFFu + ((u>>16)&1u)) >> 16);   // RNE
}
__device__ __forceinline__ int perm1020(int m){ return (m&1) ? 510+(m>>1) : (m>>1); }
__device__ __forceinline__ float gelu_exact(float x){
    return 0.5f * x * (1.f + erff(x * 0.70710678118654752f));
}
// async global->LDS, 16B per lane; LDS dest = wave-uniform base + lane*16
__device__ __forceinline__ void gll16(const u16* g, u16* l){
    __builtin_amdgcn_global_load_lds(
        (const __attribute__((address_space(1))) void*)g,
        (__attribute__((address_space(3))) void*)l, 16, 0, 0);
}

// ---------------- zero small buffer ----------------
__global__ __launch_bounds__(256)
void zero_k(float* __restrict__ p, int n)
{
    int i = blockIdx.x * 256 + threadIdx.x;
    if (i < n) p[i] = 0.f;
}

// ---------------- prep1: fold norm into qkv_w -> bf16 [640][192] + bias' [640] ----------------
__global__ __launch_bounds__(192)
void prep1_k(const float* __restrict__ w, const float* __restrict__ b,
             const float4* __restrict__ st, u16* __restrict__ wo, float* __restrict__ bo)
{
    int m = blockIdx.x, k = threadIdx.x, bz = blockIdx.y;
    st += (long)bz*192; wo += (long)bz*640*192; bo += (long)bz*640;
    float4 s = st[k];
    float wv = (m < 576) ? w[(long)m*192 + k] * s.y : 0.f;
    u16 wb = f2b(wv);
    wo[(long)m*192 + k] = wb;
    float contrib = b2f(wb) * s.x;
    for (int off = 32; off; off >>= 1) contrib += __shfl_down(contrib, off);
    __shared__ float red[3];
    if ((k & 63) == 0) red[k >> 6] = contrib;
    __syncthreads();
    if (k == 0) bo[m] = ((m < 576) ? b[m] : 0.f) - (red[0] + red[1] + red[2]);
}

// ---------------- prep2: fold norm into proj_in_w (permuted rows) -> bf16 [1024][192] ----------------
__global__ __launch_bounds__(192)
void prep2_k(const float* __restrict__ w, const float* __restrict__ b,
             const float* __restrict__ s2m, const float* __restrict__ s2r,
             u16* __restrict__ wo, float* __restrict__ bo)
{
    int m = blockIdx.x, k = threadIdx.x, bz = blockIdx.y;
    s2m += (long)bz*192; s2r += (long)bz*192; wo += (long)bz*1024*192; bo += (long)bz*1024;
    bool valid = (m < 1020);
    int src = valid ? perm1020(m) : 0;
    float wv = valid ? w[(long)src*192 + k] * s2r[k] : 0.f;
    u16 wb = f2b(wv);
    wo[(long)m*192 + k] = wb;
    float contrib = b2f(wb) * s2m[k];
    for (int off = 32; off; off >>= 1) contrib += __shfl_down(contrib, off);
    __shared__ float red[3];
    if ((k & 63) == 0) red[k >> 6] = contrib;
    __syncthreads();
    if (k == 0) bo[m] = (valid ? b[src] : 0.f) - (red[0] + red[1] + red[2]);
}

// ---------------- prep3: proj_out -> bf16 [192][512] (K padded 510->512) ----------------
__global__ __launch_bounds__(256)
void prep3_k(const float* __restrict__ w, u16* __restrict__ wo)
{
    int m = blockIdx.x;
    for (int k = threadIdx.x; k < 512; k += 256)
        wo[(long)m*512 + k] = (k < 510) ? f2b(w[(long)m*510 + k]) : (u16)0;
}

// ---------------- transpose x[c][n] f32 -> xt[n][c] bf16 + per-block stat partials ----------------
__global__ __launch_bounds__(256)
void tn_k(const float* __restrict__ xb, u16* __restrict__ xt,
          float* __restrict__ ps, float* __restrict__ pq)
{
    const int bz = blockIdx.z;
    xb += (long)bz*192*HW; xt += (long)bz*HW*192;
    ps += (long)bz*576*192; pq += (long)bz*576*192;
    __shared__ float L[64 * 196];
    long n0 = (long)blockIdx.x * 64;
    int tid = threadIdx.x;
    #pragma unroll
    for (int i = 0; i < 48; ++i) {
        int idx = tid + i*256;          // 12288 = 64n x 192c
        int n = idx & 63, c = idx >> 6;
        L[n*196 + c] = xb[(long)c*HW + n0 + n];
    }
    __syncthreads();
    if (tid < 192) {                    // per-column partials, plain stores
        float s = 0.f, q = 0.f;
        #pragma unroll 8
        for (int n = 0; n < 64; ++n) { float f = L[n*196 + tid]; s += f; q = fmaf(f, f, q); }
        ps[blockIdx.x*192 + tid] = s;
        pq[blockIdx.x*192 + tid] = q;
    }
    #pragma unroll
    for (int i = 0; i < 6; ++i) {
        int idx = tid + i*256;          // 1536 = 64n x 24oct
        int oc = idx % 24, n = idx / 24;
        ushort8 v;
        #pragma unroll
        for (int e = 0; e < 8; ++e) v[e] = f2b(L[n*196 + oc*8 + e]);
        *reinterpret_cast<ushort8*>(xt + (n0+n)*192 + oc*8) = v;
    }
}

// ---------------- reduce instnorm-1 partials: one block per column ----------------
__global__ __launch_bounds__(64)
void fin1b_k(const float* __restrict__ ps, const float* __restrict__ pq, float4* __restrict__ st)
{
    int c = blockIdx.x, t = threadIdx.x, bz = blockIdx.y;
    ps += (long)bz*576*192; pq += (long)bz*576*192; st += (long)bz*192;
    float s = 0.f, q = 0.f;
    for (int b = t; b < 576; b += 64) { s += ps[b*192 + c]; q += pq[b*192 + c]; }
    for (int off = 32; off; off >>= 1) { s += __shfl_down(s, off); q += __shfl_down(q, off); }
    if (t == 0) {
        float mean = s / (float)HW;
        float var  = q / (float)HW - mean*mean;
        st[c] = make_float4(mean, rsqrtf(var + 1e-5f), 0.f, 0.f);
    }
}

// ---------------- reduce x2 stat partials ----------------
__global__ __launch_bounds__(64)
void fin2b_k(const float* __restrict__ ps, const float* __restrict__ pq,
             float* __restrict__ m, float* __restrict__ r)
{
    int c = blockIdx.x, t = threadIdx.x, bz = blockIdx.y;
    ps += (long)bz*288*192; pq += (long)bz*288*192; m += (long)bz*192; r += (long)bz*192;
    float s = 0.f, q = 0.f;
    for (int b = t; b < 288; b += 64) { s += ps[b*192 + c]; q += pq[b*192 + c]; }
    for (int off = 32; off; off >>= 1) { s += __shfl_down(s, off); q += __shfl_down(q, off); }
    if (t == 0) {
        float mean = s / (float)HW;
        float var  = q / (float)HW - mean*mean;
        m[c] = mean;
        r[c] = rsqrtf(var + 1e-5f);
    }
}

// ---------------- MFMA GEMM: out[n][m] = sum_k B[n][k] * W[m][k] ----------------
// OUTT: 0 = bf16 [n][m]; 1 = f32 [m][n] (BM=64); 2 = bf16 [m][n] planar (BM=128)
// RESID==1 additionally emits per-block x2 column-stat partials (no atomics)
template<int BM, int RESID, int OUTT>
__global__ __launch_bounds__(256)
void gemm_k(const u16* __restrict__ W, int Kpad, int K64, long wstr,
            const u16* __restrict__ B, int brs, long bstr,
            const float* __restrict__ bias, int biasstr,
            const u16* __restrict__ Rs, long rstr,
            u16* __restrict__ outA, int ors, long ostr, int Mout,
            float* __restrict__ outT, long otstr,
            float* __restrict__ p2s, float* __restrict__ p2q)
{
    constexpr int MR  = BM / 64;
    constexpr int OLS = (OUTT==0) ? (BM+8) : 130;
    constexpr int L_MAIN = 8192 + BM*64;
    constexpr int L_OUT  = (OUTT==0) ? 128*OLS : BM*130;
    constexpr int LDSU = L_MAIN > L_OUT ? L_MAIN : L_OUT;
    __shared__ u16 lds[LDSU];
    __shared__ float cws[256], cwq[256];
    u16* Xl = lds;              // [128][64] swizzled
    u16* Wl = lds + 8192;       // [BM][64]  swizzled

    const int bz = blockIdx.z;
    W += (long)bz*wstr; B += (long)bz*bstr; bias += (long)bz*biasstr;
    if (RESID) Rs += (long)bz*rstr;
    if (OUTT==1) outT += (long)bz*otstr; else outA += (long)bz*ostr;

    const int tid = threadIdx.x;
    const int m0 = blockIdx.x * BM;
    const long nn0 = (long)blockIdx.y * 128;
    const int ln = tid & 63, wv = tid >> 6;
    const int wn = (wv >> 1) * 64;
    const int wm = (wv & 1) * (BM/2);
    const int l31 = ln & 31, l5 = ln >> 5;

    const u16* Bb = B + nn0*(long)brs;
    const u16* Wb = W + (long)m0*Kpad;

    f32x16 acc[2][MR];
    #pragma unroll
    for (int a = 0; a < 2; ++a)
        #pragma unroll
        for (int b = 0; b < MR; ++b)
            #pragma unroll
            for (int r = 0; r < 16; ++r) acc[a][b][r] = 0.f;

    for (int ks = 0; ks < K64; ++ks) {
        #pragma unroll
        for (int i = 0; i < 4; ++i) {
            int chunk = i*256 + tid;
            int row = chunk >> 3, o = chunk & 7;
            int op = o ^ ((row >> 1) & 7);
            gll16(Bb + (long)row*brs + ks*64 + op*8, Xl + chunk*8);
        }
        #pragma unroll
        for (int i = 0; i < BM/32; ++i) {
            int chunk = i*256 + tid;
            int row = chunk >> 3, o = chunk & 7;
            int op = o ^ ((row >> 1) & 7);
            gll16(Wb + (long)row*Kpad + ks*64 + op*8, Wl + chunk*8);
        }
        __syncthreads();
        #pragma unroll
        for (int k16 = 0; k16 < 4; ++k16) {
            short8 af[2];
            #pragma unroll
            for (int nr = 0; nr < 2; ++nr) {
                int row = wn + nr*32 + l31;
                int slot = (k16*2 + l5) ^ ((row >> 1) & 7);
                af[nr] = *reinterpret_cast<const short8*>(&Xl[row*64 + slot*8]);
            }
            short8 bf[MR];
            #pragma unroll
            for (int mr = 0; mr < MR; ++mr) {
                int rowm = wm + mr*32 + l31;
                int slot = (k16*2 + l5) ^ ((rowm >> 1) & 7);
                bf[mr] = *reinterpret_cast<const short8*>(&Wl[rowm*64 + slot*8]);
            }
            #pragma unroll
            for (int nr = 0; nr < 2; ++nr)
                #pragma unroll
                for (int mr = 0; mr < MR; ++mr)
                    acc[nr][mr] = __builtin_amdgcn_mfma_f32_32x32x16_bf16(af[nr], bf[mr], acc[nr][mr], 0, 0, 0);
        }
        __syncthreads();
    }
    float bsv[MR];
    #pragma unroll
    for (int mr = 0; mr < MR; ++mr)
        bsv[mr] = bias[m0 + wm + mr*32 + l31];
    u16* Ol = lds;
    #pragma unroll
    for (int nr = 0; nr < 2; ++nr)
        #pragma unroll
        for (int mr = 0; mr < MR; ++mr)
            #pragma unroll
            for (int reg = 0; reg < 16; ++reg) {
                int r32 = (reg & 3) + 8*(reg >> 2) + 4*l5;
                int grow = wn + nr*32 + r32;
                int gcol = wm + mr*32 + l31;
                float val = acc[nr][mr][reg] + bsv[mr];
                if (RESID == 2)
                    val += b2f(Rs[(nn0 + grow)*192 + m0 + gcol]);
                if (OUTT == 0) Ol[grow*OLS + gcol] = f2b(val);
                else           Ol[gcol*130 + grow] = f2b(val);
            }
    __syncthreads();
    if (OUTT == 0) {
        constexpr int SPR = BM/8;
        float ls[8] = {0,0,0,0,0,0,0,0}, lq[8] = {0,0,0,0,0,0,0,0};
        #pragma unroll
        for (int i = 0; i < 128*SPR/256; ++i) {
            int idx = tid + i*256;
            int row = idx / SPR, sl = idx % SPR;
            if (m0 + sl*8 >= Mout) continue;
            ushort8 v = *reinterpret_cast<const ushort8*>(&Ol[row*OLS + sl*8]);
            if (RESID == 1) {
                ushort8 rv = *reinterpret_cast<const ushort8*>(Rs + (nn0+row)*(long)ors + m0 + sl*8);
                #pragma unroll
                for (int e = 0; e < 8; ++e) {
                    v[e] = f2b(b2f(v[e]) + b2f(rv[e]));
                    float vv = b2f(v[e]);
                    ls[e] += vv; lq[e] = fmaf(vv, vv, lq[e]);
                }
            }
            *reinterpret_cast<ushort8*>(outA + (nn0+row)*(long)ors + m0 + sl*8) = v;
        }
        if (RESID == 1) {
            #pragma unroll
            for (int e = 0; e < 8; ++e) {
                float s = ls[e], q = lq[e];
                s += __shfl_xor(s, 8);  q += __shfl_xor(q, 8);
                s += __shfl_xor(s, 16); q += __shfl_xor(q, 16);
                s += __shfl_xor(s, 32); q += __shfl_xor(q, 32);
                if (ln < 8) { cws[wv*64 + ln*8 + e] = s; cwq[wv*64 + ln*8 + e] = q; }
            }
            __syncthreads();
            if (tid < 64) {
                float s = cws[tid] + cws[64+tid] + cws[128+tid] + cws[192+tid];
                float q = cwq[tid] + cwq[64+tid] + cwq[128+tid] + cwq[192+tid];
                p2s[(long)bz*288*192 + blockIdx.y*192 + m0 + tid] = s;
                p2q[(long)bz*288*192 + blockIdx.y*192 + m0 + tid] = q;
            }
        }
    } else if (OUTT == 1) {
        // f32 transposed out (BM=64): Ol is [m][n] pitch 130
        int m = tid >> 2, ng = tid & 3;
        float* orow = outT + (long)(m0 + m)*HW + nn0 + ng*32;
        #pragma unroll
        for (int i = 0; i < 32; i += 8) {
            ushort8 v = *reinterpret_cast<const ushort8*>(&Ol[m*130 + ng*32 + i]);
            float4 o1 = make_float4(b2f(v[0]), b2f(v[1]), b2f(v[2]), b2f(v[3]));
            float4 o2 = make_float4(b2f(v[4]), b2f(v[5]), b2f(v[6]), b2f(v[7]));
            *reinterpret_cast<float4*>(orow + i)     = o1;
            *reinterpret_cast<float4*>(orow + i + 4) = o2;
        }
    } else {
        // bf16 planar out (BM=128): Ol is [m][n] pitch 130
        int m = tid >> 1, ng = tid & 1;
        if (m0 + m < Mout) {
            u16* orow = outA + (long)(m0 + m)*HW + nn0 + ng*64;
            #pragma unroll
            for (int i = 0; i < 64; i += 8)
                *reinterpret_cast<ushort8*>(orow + i) =
                    *reinterpret_cast<const ushort8*>(&Ol[m*130 + ng*64 + i]);
        }
    }
}

// ---------------- dwq: planar depthwise 3x3 on q/k planes + fused sumsq ----------------
__global__ __launch_bounds__(256)
void dwq_k(const u16* __restrict__ t1P, const float* __restrict__ dww,
           const float* __restrict__ dwb, u16* __restrict__ qkP,
           float* __restrict__ nacc, const u16* __restrict__ zp)
{
    const int bz = blockIdx.z;
    t1P += (long)bz*HW*576; qkP += (long)bz*384*(long)HW; nacc += (long)bz*384;
    const int plane = blockIdx.y;          // 0..383 (q then k channels)
    const int y0 = blockIdx.x * 16;
    __shared__ u16 Ts[18*192];             // 6912 B, full-width rows + y halo
    __shared__ float wq[10];
    __shared__ float wsum[4];
    const int tid = threadIdx.x;
    if (tid < 9) wq[tid] = dww[plane*9 + tid];
    if (tid == 9) wq[9] = dwb[plane];
    const u16* pl = t1P + (long)plane*HW;
    for (int i = tid; i < 432; i += 256) {     // 18 rows x 24 chunks
        int r = i / 24, c8 = i - r*24;
        int gy = y0 - 1 + r;
        const u16* src = ((unsigned)gy < 192u) ? pl + gy*192 + c8*8 : zp;
        gll16(src, Ts + i*8);
    }
    __syncthreads();
    float w[9];
    #pragma unroll
    for (int j = 0; j < 9; ++j) w[j] = wq[j];
    const float bias = wq[9];
    float sq = 0.f;
    for (int cc = tid; cc < 384; cc += 256) {  // 16 rows x 24 chunks of 8 px
        int y = cc / 24, x8 = cc - y*24;
        float a[8];
        #pragma unroll
        for (int e = 0; e < 8; ++e) a[e] = bias;
        #pragma unroll
        for (int dy = 0; dy < 3; ++dy) {
            const u16* R = &Ts[(y+dy)*192];
            ushort8 mid = *reinterpret_cast<const ushort8*>(&R[x8*8]);
            ushort8 lft = x8       ? *reinterpret_cast<const ushort8*>(&R[x8*8-8]) : (ushort8)0;
            ushort8 rgt = (x8<23)  ? *reinterpret_cast<const ushort8*>(&R[x8*8+8]) : (ushort8)0;
            float v[10];
            v[0] = b2f(lft[7]);
            #pragma unroll
            for (int e = 0; e < 8; ++e) v[1+e] = b2f(mid[e]);
            v[9] = b2f(rgt[0]);
            #pragma unroll
            for (int dx = 0; dx < 3; ++dx)
                #pragma unroll
                for (int e = 0; e < 8; ++e)
                    a[e] = fmaf(v[e+dx], w[dy*3+dx], a[e]);
        }
        ushort8 ov;
        #pragma unroll
        for (int e = 0; e < 8; ++e) { ov[e] = f2b(a[e]); sq = fmaf(a[e], a[e], sq); }
        *reinterpret_cast<ushort8*>(qkP + (long)plane*HW + (y0+y)*192 + x8*8) = ov;
    }
    for (int off = 32; off; off >>= 1) sq += __shfl_down(sq, off);
    if ((tid & 63) == 0) wsum[tid >> 6] = sq;
    __syncthreads();
    if (tid == 0) atomicAdd(&nacc[plane], wsum[0]+wsum[1]+wsum[2]+wsum[3]);
}

// ---------------- dwv: planar depthwise 3x3 on v planes + transpose to vbuf[n][192] ----------------
__global__ __launch_bounds__(256)
void dwv_k(const u16* __restrict__ t1P, const float* __restrict__ dww,
           const float* __restrict__ dwb, u16* __restrict__ vbuf,
           const u16* __restrict__ zp)
{
    const int bz = blockIdx.z;
    t1P += (long)bz*HW*576; vbuf += (long)bz*HW*192;
    const int cg = blockIdx.y;                 // 0..23, 8 v-channels each
    const int ty = blockIdx.x / 6, tx = blockIdx.x % 6;
    const int y0 = ty*8, x0 = tx*32;
    __shared__ u16 Tv[8*10*48];                // 7680 B: 8 ch x 10 rows x 48 px (x-halo'd)
    __shared__ u16 T2[256*8];                  // 4096 B transpose buffer
    __shared__ float wl[8][9];
    __shared__ float bl[8];
    const int tid = threadIdx.x;
    for (int i = tid; i < 72; i += 256) wl[i/9][i%9] = dww[(long)(384 + cg*8 + i/9)*9 + i%9];
    if (tid < 8) bl[tid] = dwb[384 + cg*8 + tid];
    for (int i = tid; i < 480; i += 256) {     // 8 ch x 10 rows x 6 chunks
        int o = i / 60; int rem = i - o*60;
        int r = rem / 6, c8 = rem - r*6;
        int gy = y0 - 1 + r;
        int gx0 = x0 - 8 + c8*8;
        const u16* src = ((unsigned)gy < 192u && (unsigned)gx0 <= 184u)
            ? t1P + (long)(384 + cg*8 + o)*HW + gy*192 + gx0 : zp;
        gll16(src, Tv + i*8);
    }
    __syncthreads();
    const int o = tid >> 5, xc = tid & 31;
    float w[9];
    #pragma unroll
    for (int j = 0; j < 9; ++j) w[j] = wl[o][j];
    const float bias = bl[o];
    const u16* base = &Tv[o*480];              // [10][48]
    #pragma unroll
    for (int y = 0; y < 8; ++y) {
        float a = bias;
        #pragma unroll
        for (int dy = 0; dy < 3; ++dy) {
            const u16* R = base + (y+dy)*48 + xc + 7;  // local col xc+dx+7
            a = fmaf(b2f(R[0]), w[dy*3+0], a);
            a = fmaf(b2f(R[1]), w[dy*3+1], a);
            a = fmaf(b2f(R[2]), w[dy*3+2], a);
        }
        T2[(y*32 + xc)*8 + o] = f2b(a);
    }
    __syncthreads();
    const int px = tid;
    const int yy = px >> 5, xx = px & 31;
    *reinterpret_cast<ushort8*>(vbuf + ((long)(y0+yy)*192 + x0+xx)*192 + cg*8) =
        *reinterpret_cast<const ushort8*>(&T2[px*8]);
}

// ---------------- MFMA attention scores: apart[ns][h][c*48+d] = sum_n q·k over n-chunk ----------------
__global__ __launch_bounds__(256)
void attnscore_k(const u16* __restrict__ qkT, float* __restrict__ apart)
{
    const int bz = blockIdx.z;
    qkT += (long)bz*384*HW; apart += (long)bz*72*9216;
    __shared__ u16 lds[8192];           // A[64][64] + B[64][64] swizzled
    u16* Al = lds;
    u16* Bl = lds + 4096;
    const int tid = threadIdx.x;
    const int h = blockIdx.y;
    const long nb = (long)blockIdx.x * 512;
    const int ln = tid & 63, wv = tid >> 6;
    const int wq = (wv >> 1) * 32, wd = (wv & 1) * 32;
    const int l31 = ln & 31, l5 = ln >> 5;

    f32x16 acc;
    #pragma unroll
    for (int r = 0; r < 16; ++r) acc[r] = 0.f;

    for (int ks = 0; ks < 8; ++ks) {
        #pragma unroll
        for (int i = 0; i < 2; ++i) {
            int chunk = i*256 + tid;
            int row = chunk >> 3, o = chunk & 7;
            int op = o ^ ((row >> 1) & 7);
            int qr = h*48 + (row < 48 ? row : 0);
            gll16(qkT + (long)qr*HW + nb + ks*64 + op*8, Al + chunk*8);
        }
        #pragma unroll
        for (int i = 0; i < 2; ++i) {
            int chunk = i*256 + tid;
            int row = chunk >> 3, o = chunk & 7;
            int op = o ^ ((row >> 1) & 7);
            int kr = 192 + h*48 + (row < 48 ? row : 0);
            gll16(qkT + (long)kr*HW + nb + ks*64 + op*8, Bl + chunk*8);
        }
        __syncthreads();
        #pragma unroll
        for (int k16 = 0; k16 < 4; ++k16) {
            int rq = wq + l31;
            int sq_ = (k16*2 + l5) ^ ((rq >> 1) & 7);
            short8 af = *reinterpret_cast<const short8*>(&Al[rq*64 + sq_*8]);
            int rk = wd + l31;
            int sk = (k16*2 + l5) ^ ((rk >> 1) & 7);
            short8 bf = *reinterpret_cast<const short8*>(&Bl[rk*64 + sk*8]);
            acc = __builtin_amdgcn_mfma_f32_32x32x16_bf16(af, bf, acc, 0, 0, 0);
        }
        __syncthreads();
    }
    float* ap = apart + ((long)blockIdx.x*4 + h) * 2304;
    #pragma unroll
    for (int reg = 0; reg < 16; ++reg) {
        int c = wq + (reg & 3) + 8*(reg >> 2) + 4*l5;
        int d = wd + l31;
        if (c < 48 && d < 48) ap[c*48 + d] = acc[reg];
    }
}

// ---------------- reduce split-n partials ----------------
__global__ __launch_bounds__(256)
void red_k(const float* __restrict__ apart, float* __restrict__ araw)
{
    const int bz = blockIdx.y;
    apart += (long)bz*72*9216; araw += (long)bz*9216;
    int idx = blockIdx.x*256 + threadIdx.x;   // 9216
    float s = 0.f;
    for (int p = 0; p < 72; ++p) s += apart[(long)p*9216 + idx];
    araw[idx] = s;
}

// ---------------- softmax (all heads, register rows) -> ssm f32 ----------------
__global__ __launch_bounds__(256)
void softmax_sm_k(const float* __restrict__ araw, const float* __restrict__ nacc,
                  const float* __restrict__ temp, float* __restrict__ ssm)
{
    const int bz = blockIdx.x;
    araw += (long)bz*9216; nacc += (long)bz*384; ssm += (long)bz*9216;
    int tid = threadIdx.x;
    if (tid >= 192) return;
    int h = tid / 48, c = tid % 48;
    float qn = fmaxf(sqrtf(nacc[h*48 + c]), 1e-12f);
    float ti = temp[h] / qn;
    const float* ar = araw + h*2304 + c*48;
    const float* nk = nacc + 192 + h*48;
    float row[48];
    float mx = -1e30f;
    #pragma unroll
    for (int d = 0; d < 48; ++d) {
        float kn = fmaxf(sqrtf(nk[d]), 1e-12f);
        row[d] = ar[d] * ti / kn;
        mx = fmaxf(mx, row[d]);
    }
    float ssum = 0.f;
    #pragma unroll
    for (int d = 0; d < 48; ++d) { float e = expf(row[d] - mx); row[d] = e; ssum += e; }
    float inv = 1.f / ssum;
    float* so = ssm + h*2304 + c*48;
    #pragma unroll
    for (int d = 0; d < 48; ++d) so[d] = row[d] * inv;
}

// ---------------- fold softmax into attn_out_w -> bf16 W2b [192][192] ----------------
__global__ __launch_bounds__(256)
void w2fold_k(const float* __restrict__ ssm, const float* __restrict__ aow,
              u16* __restrict__ W2b)
{
    const int bz = blockIdx.y;
    ssm += (long)bz*9216; W2b += (long)bz*36864;
    int idx = blockIdx.x*256 + threadIdx.x;    // 36864
    int o = idx / 192, col = idx % 192;
    int h = col / 48, d = col % 48;
    const float* ar = aow + (long)o*192 + h*48;
    const float* sp = ssm + h*2304 + d;
    float s = 0.f;
    #pragma unroll
    for (int c = 0; c < 48; ++c) s = fmaf(ar[c], sp[c*48], s);
    W2b[idx] = f2b(s);
}

// ---------------- gate: depthwise 3x3 pairs + GELU, gll16 staging + sliding window ----------------
__global__ __launch_bounds__(256)
void gate_k(const u16* __restrict__ t2h, const float* __restrict__ dww,
            const float* __restrict__ dwb, u16* __restrict__ g, int jbase,
            const u16* __restrict__ zp)
{
    const int bz = blockIdx.z;
    t2h += (long)bz*HW*512; g += (long)bz*HW*576;
    __shared__ u16 T[10*34*32];        // 21760 B
    __shared__ float w1l[16][9], w2l[16][9];
    __shared__ float b1l[16], b2l[16];
    const int tid = threadIdx.x;
    const int cg = blockIdx.y;                       // 0..15 -> 32 u16 cols = 16 pairs
    const int ty = blockIdx.x / 6, tx = blockIdx.x % 6;
    const int y0 = ty*8, x0 = tx*32;
    const int jb = jbase + cg*16;

    for (int i = tid; i < 144; i += 256) {
        int p = i/9, j = i%9;
        int gj = jb + p;
        bool ok = (gj < 510);
        w1l[p][j] = ok ? dww[(long)gj*9 + j] : 0.f;
        w2l[p][j] = ok ? dww[(long)(510+gj)*9 + j] : 0.f;
    }
    if (tid < 16) {
        int gj = jb + tid;
        bool ok = (gj < 510);
        b1l[tid] = ok ? dwb[gj] : 0.f;
        b2l[tid] = ok ? dwb[510+gj] : 0.f;
    }
    #pragma unroll
    for (int it = 0; it < 6; ++it) {
        int i = it*256 + tid;
        if (i < 1360) {
            int r = i / 136;
            int rem = i - r*136;
            int c = rem >> 2, o = rem & 3;
            int gy = y0 - 1 + r, gx = x0 - 1 + c;
            const u16* src = ((unsigned)gy < 192u && (unsigned)gx < 192u)
                ? t2h + ((long)gy*192 + gx)*512 + cg*32 + o*8 : zp;
            gll16(src, T + i*8);
        }
    }
    __syncthreads();

    const int o2 = tid & 3, xc = (tid >> 2) & 31, yh = tid >> 7;
    float w1r[4][9], w2r[4][9], b1r[4], b2r[4];
    #pragma unroll
    for (int p = 0; p < 4; ++p) {
        #pragma unroll
        for (int j = 0; j < 9; ++j) { w1r[p][j] = w1l[o2*4+p][j]; w2r[p][j] = w2l[o2*4+p][j]; }
        b1r[p] = b1l[o2*4+p]; b2r[p] = b2l[o2*4+p];
    }
    float a1[4][4], a2[4][4];
    #pragma unroll
    for (int yy = 0; yy < 4; ++yy)
        #pragma unroll
        for (int p = 0; p < 4; ++p) { a1[yy][p] = b1r[p]; a2[yy][p] = b2r[p]; }
    #pragma unroll
    for (int r = 0; r < 6; ++r) {
        const int rr = yh*4 + r;
        float f1[3][4], f2[3][4];
        #pragma unroll
        for (int dx = 0; dx < 3; ++dx) {
            ushort8 v = *reinterpret_cast<const ushort8*>(&T[(rr*34 + xc+dx)*32 + o2*8]);
            #pragma unroll
            for (int p = 0; p < 4; ++p) { f1[dx][p] = b2f(v[2*p]); f2[dx][p] = b2f(v[2*p+1]); }
        }
        #pragma unroll
        for (int yy = 0; yy < 4; ++yy) {
            const int dy = r - yy;
            if (dy < 0 || dy > 2) continue;
            #pragma unroll
            for (int dx = 0; dx < 3; ++dx)
                #pragma unroll
                for (int p = 0; p < 4; ++p) {
                    a1[yy][p] = fmaf(f1[dx][p], w1r[p][dy*3+dx], a1[yy][p]);
                    a2[yy][p] = fmaf(f2[dx][p], w2r[p][dy*3+dx], a2[yy][p]);
                }
        }
    }
    #pragma unroll
    for (int yy = 0; yy < 4; ++yy) {
        int y = yh*4 + yy;
        ushort4 ovv;
        ovv.x = f2b(gelu_exact(a1[yy][0]) * a2[yy][0]);
        ovv.y = f2b(gelu_exact(a1[yy][1]) * a2[yy][1]);
        ovv.z = f2b(gelu_exact(a1[yy][2]) * a2[yy][2]);
        ovv.w = f2b(gelu_exact(a1[yy][3]) * a2[yy][3]);
        *reinterpret_cast<ushort4*>(g + ((long)(y0+y)*192 + x0+xc)*512 + jb + o2*4) = ovv;
    }
}

extern "C" void kernel_launch(void* const* d_in, const int* in_sizes, int n_in,
                              void* d_out, int out_size, void* d_ws, size_t ws_size,
                              hipStream_t stream) {
    const float* x           = (const float*)d_in[0];
    const float* qkv_w       = (const float*)d_in[1];
    const float* qkv_bias    = (const float*)d_in[2];
    const float* qkv_dw_w    = (const float*)d_in[3];
    const float* qkv_dw_b    = (const float*)d_in[4];
    const float* attn_out_w  = (const float*)d_in[5];
    const float* attn_out_b  = (const float*)d_in[6];
    const float* temperature = (const float*)d_in[7];
    const float* proj_in_w   = (const float*)d_in[8];
    const float* proj_in_b   = (const float*)d_in[9];
    const float* dw_w        = (const float*)d_in[10];
    const float* dw_b        = (const float*)d_in[11];
    const float* proj_out_w  = (const float*)d_in[12];
    const float* proj_out_b  = (const float*)d_in[13];
    float* out = (float*)d_out;
    char* ws = (char*)d_ws;

    const bool batched = (ws_size >= 210000000ull);
    const long nb = batched ? 2 : 1;

    const long ASZ = (long)HW*192*2;
    const long CSZ = (long)HW*576*2;
    const long VSZ = (long)HW*192*2;
    const long QSZ = (long)384*HW*2;
    u16* A_   = (u16*)ws;
    u16* C_   = (u16*)(ws + nb*ASZ);          // t1P planar [576][HW] -> g[n][512]
    u16* vbuf = (u16*)(ws + nb*(ASZ + CSZ));
    u16* qkP  = (u16*)(ws + nb*(ASZ + CSZ + VSZ));   // [384][HW]
    u16* E_   = vbuf;                          // t2half [n][512] aliases vbuf+qkP
    char* wsm = ws + nb*(ASZ + CSZ + VSZ + QSZ);
    u16* W1p = (u16*)(wsm);
    u16* W2p = (u16*)(wsm + nb*245760);
    u16* W3p = (u16*)(wsm + nb*(245760 + 393216));
    u16* W2b = (u16*)(wsm + nb*(245760 + 393216) + 196608);
    float* b1p = (float*)(wsm + nb*(245760 + 393216 + 73728) + 196608);
    float* b2p = b1p + nb*640;
    float* S_  = b2p + nb*1024;
    float* zpadf = S_;                       // 8
    float* nacc  = S_ + 8;                   // nb*384
    float* araw  = nacc + nb*384;            // nb*9216
    float* ssm   = araw + nb*9216;           // nb*9216
    float4* st1  = (float4*)(ssm + nb*9216); // nb*192
    float* s2m   = (float*)(st1 + nb*192);
    float* s2r   = s2m + nb*192;
    float* apart = s2r + nb*192;             // nb*72*9216
    float* p1s = apart;
    float* p1q = apart + nb*110592;
    float* p2s = apart;
    float* p2q = apart + nb*55296;
    const u16* zp = (const u16*)zpadf;

    const long AE = (long)HW*192;
    const long CE = (long)HW*576;
    const long VE = (long)HW*192;
    const long EE = (long)HW*512;

    prep3_k<<<192, 256, 0, stream>>>(proj_out_w, W3p);

    if (batched) {
        zero_k<<<4, 256, 0, stream>>>(S_, 8 + 2*384);
        tn_k<<<dim3(576,1,2), 256, 0, stream>>>(x, A_, p1s, p1q);
        fin1b_k<<<dim3(192,2), 64, 0, stream>>>(p1s, p1q, st1);
        prep1_k<<<dim3(640,2), 192, 0, stream>>>(qkv_w, qkv_bias, st1, W1p, b1p);

        // G1: t1P[m][n] planar = (xt @ W1p^T + b1p)^T
        gemm_k<128,0,2><<<dim3(5,288,2), 256, 0, stream>>>(
            W1p, 192, 3, 640*192, A_, 192, AE, b1p, 640, nullptr, 0, C_, 0, CE, 576, nullptr, 0, nullptr, nullptr);
        dwq_k<<<dim3(12,384,2), 256, 0, stream>>>(C_, qkv_dw_w, qkv_dw_b, qkP, nacc, zp);
        dwv_k<<<dim3(144,24,2), 256, 0, stream>>>(C_, qkv_dw_w, qkv_dw_b, vbuf, zp);
        attnscore_k<<<dim3(72,4,2), 256, 0, stream>>>(qkP, apart);
        red_k<<<dim3(36,2), 256, 0, stream>>>(apart, araw);
        softmax_sm_k<<<2, 256, 0, stream>>>(araw, nacc, temperature, ssm);
        w2fold_k<<<dim3(144,2), 256, 0, stream>>>(ssm, attn_out_w, W2b);
        gemm_k<64,1,0><<<dim3(3,288,2), 256, 0, stream>>>(
            W2b, 192, 3, 36864, vbuf, 192, VE, attn_out_b, 0, A_, AE, A_, 192, AE, 192, nullptr, 0, p2s, p2q);

        fin2b_k<<<dim3(192,2), 64, 0, stream>>>(p2s, p2q, s2m, s2r);
        prep2_k<<<dim3(1024,2), 192, 0, stream>>>(proj_in_w, proj_in_b, s2m, s2r, W2p, b2p);

        gemm_k<128,0,0><<<dim3(4,288,2), 256, 0, stream>>>(
            W2p, 192, 3, 1024*192, A_, 192, AE, b2p, 1024, nullptr, 0, E_, 512, EE, 512, nullptr, 0, nullptr, nullptr);
        gate_k<<<dim3(144,16,2), 256, 0, stream>>>(E_, dw_w, dw_b, C_, 0, zp);
        gemm_k<128,0,0><<<dim3(4,288,2), 256, 0, stream>>>(
            W2p + (long)512*192, 192, 3, 1024*192, A_, 192, AE, b2p + 512, 1024, nullptr, 0, E_, 512, EE, 512, nullptr, 0, nullptr, nullptr);
        gate_k<<<dim3(144,16,2), 256, 0, stream>>>(E_, dw_w, dw_b, C_, 256, zp);

        gemm_k<64,2,1><<<dim3(3,288,2), 256, 0, stream>>>(
            W3p, 512, 8, 0, C_, 512, CE, proj_out_b, 0, A_, AE, nullptr, 0, 0, 192, out, (long)192*HW, nullptr, nullptr);
    } else {
        for (int b = 0; b < 2; ++b) {
            const float* xb = x + (long)b * 192 * HW;
            float* outb = out + (long)b * 192 * HW;

            zero_k<<<2, 256, 0, stream>>>(S_, 8 + 384);
            tn_k<<<dim3(576,1,1), 256, 0, stream>>>(xb, A_, p1s, p1q);
            fin1b_k<<<dim3(192,1), 64, 0, stream>>>(p1s, p1q, st1);
            prep1_k<<<dim3(640,1), 192, 0, stream>>>(qkv_w, qkv_bias, st1, W1p, b1p);

            gemm_k<128,0,2><<<dim3(5,288,1), 256, 0, stream>>>(
                W1p, 192, 3, 0, A_, 192, 0, b1p, 0, nullptr, 0, C_, 0, 0, 576, nullptr, 0, nullptr, nullptr);
            dwq_k<<<dim3(12,384,1), 256, 0, stream>>>(C_, qkv_dw_w, qkv_dw_b, qkP, nacc, zp);
            dwv_k<<<dim3(144,24,1), 256, 0, stream>>>(C_, qkv_dw_w, qkv_dw_b, vbuf, zp);
            attnscore_k<<<dim3(72,4,1), 256, 0, stream>>>(qkP, apart);
            red_k<<<dim3(36,1), 256, 0, stream>>>(apart, araw);
            softmax_sm_k<<<1, 256, 0, stream>>>(araw, nacc, temperature, ssm);
            w2fold_k<<<dim3(144,1), 256, 0, stream>>>(ssm, attn_out_w, W2b);
            gemm_k<64,1,0><<<dim3(3,288,1), 256, 0, stream>>>(
                W2b, 192, 3, 0, vbuf, 192, 0, attn_out_b, 0, A_, 0, A_, 192, 0, 192, nullptr, 0, p2s, p2q);

            fin2b_k<<<dim3(192,1), 64, 0, stream>>>(p2s, p2q, s2m, s2r);
            prep2_k<<<dim3(1024,1), 192, 0, stream>>>(proj_in_w, proj_in_b, s2m, s2r, W2p, b2p);

            gemm_k<128,0,0><<<dim3(4,288,1), 256, 0, stream>>>(
                W2p, 192, 3, 0, A_, 192, 0, b2p, 0, nullptr, 0, E_, 512, 0, 512, nullptr, 0, nullptr, nullptr);
            gate_k<<<dim3(144,16,1), 256, 0, stream>>>(E_, dw_w, dw_b, C_, 0, zp);
            gemm_k<128,0,0><<<dim3(4,288,1), 256, 0, stream>>>(
                W2p + (long)512*192, 192, 3, 0, A_, 192, 0, b2p + 512, 0, nullptr, 0, E_, 512, 0, 512, nullptr, 0, nullptr, nullptr);
            gate_k<<<dim3(144,16,1), 256, 0, stream>>>(E_, dw_w, dw_b, C_, 256, zp);

            gemm_k<64,2,1><<<dim3(3,288,1), 256, 0, stream>>>(
                W3p, 512, 8, 0, C_, 512, 0, proj_out_b, 0, A_, 0, nullptr, 0, 0, 192, outb, 0, nullptr, nullptr);
        }
    }
}

// Round 13
// 386.976 us; speedup vs baseline: 1.0400x; 1.0400x over previous
//
#include <hip/hip_runtime.h>
#include <math.h>

#define HW 36864
#define IMGW 192

typedef unsigned short u16;
typedef __attribute__((ext_vector_type(8))) short short8;
typedef __attribute__((ext_vector_type(8))) unsigned short ushort8;
typedef __attribute__((ext_vector_type(16))) float f32x16;

__device__ __forceinline__ float b2f(u16 u){ return __uint_as_float(((unsigned)u)<<16); }
__device__ __forceinline__ u16 f2b(float f){
    unsigned u = __float_as_uint(f);
    return (u16)((u + 0x7FFFu + ((u>>16)&1u)) >> 16);   // RNE
}
__device__ __forceinline__ int perm1020(int m){ return (m&1) ? 510+(m>>1) : (m>>1); }
__device__ __forceinline__ float gelu_exact(float x){
    return 0.5f * x * (1.f + erff(x * 0.70710678118654752f));
}
// async global->LDS, 16B per lane; LDS dest = wave-uniform base + lane*16
__device__ __forceinline__ void gll16(const u16* g, u16* l){
    __builtin_amdgcn_global_load_lds(
        (const __attribute__((address_space(1))) void*)g,
        (__attribute__((address_space(3))) void*)l, 16, 0, 0);
}

// ---------------- zero small buffer ----------------
__global__ __launch_bounds__(256)
void zero_k(float* __restrict__ p, int n)
{
    int i = blockIdx.x * 256 + threadIdx.x;
    if (i < n) p[i] = 0.f;
}

// ---------------- prep1: fold norm into qkv_w -> bf16 [640][192] + bias' [640] ----------------
__global__ __launch_bounds__(192)
void prep1_k(const float* __restrict__ w, const float* __restrict__ b,
             const float4* __restrict__ st, u16* __restrict__ wo, float* __restrict__ bo)
{
    int m = blockIdx.x, k = threadIdx.x, bz = blockIdx.y;
    st += (long)bz*192; wo += (long)bz*640*192; bo += (long)bz*640;
    float4 s = st[k];
    float wv = (m < 576) ? w[(long)m*192 + k] * s.y : 0.f;
    u16 wb = f2b(wv);
    wo[(long)m*192 + k] = wb;
    float contrib = b2f(wb) * s.x;
    for (int off = 32; off; off >>= 1) contrib += __shfl_down(contrib, off);
    __shared__ float red[3];
    if ((k & 63) == 0) red[k >> 6] = contrib;
    __syncthreads();
    if (k == 0) bo[m] = ((m < 576) ? b[m] : 0.f) - (red[0] + red[1] + red[2]);
}

// ---------------- prep2: fold norm into proj_in_w (permuted rows) -> bf16 [1024][192] ----------------
__global__ __launch_bounds__(192)
void prep2_k(const float* __restrict__ w, const float* __restrict__ b,
             const float* __restrict__ s2m, const float* __restrict__ s2r,
             u16* __restrict__ wo, float* __restrict__ bo)
{
    int m = blockIdx.x, k = threadIdx.x, bz = blockIdx.y;
    s2m += (long)bz*192; s2r += (long)bz*192; wo += (long)bz*1024*192; bo += (long)bz*1024;
    bool valid = (m < 1020);
    int src = valid ? perm1020(m) : 0;
    float wv = valid ? w[(long)src*192 + k] * s2r[k] : 0.f;
    u16 wb = f2b(wv);
    wo[(long)m*192 + k] = wb;
    float contrib = b2f(wb) * s2m[k];
    for (int off = 32; off; off >>= 1) contrib += __shfl_down(contrib, off);
    __shared__ float red[3];
    if ((k & 63) == 0) red[k >> 6] = contrib;
    __syncthreads();
    if (k == 0) bo[m] = (valid ? b[src] : 0.f) - (red[0] + red[1] + red[2]);
}

// ---------------- prep3: proj_out -> bf16 [192][512] (K padded 510->512) ----------------
__global__ __launch_bounds__(256)
void prep3_k(const float* __restrict__ w, u16* __restrict__ wo)
{
    int m = blockIdx.x;
    for (int k = threadIdx.x; k < 512; k += 256)
        wo[(long)m*512 + k] = (k < 510) ? f2b(w[(long)m*510 + k]) : (u16)0;
}

// ---------------- transpose x[c][n] f32 -> xt[n][c] bf16 + per-block stat partials ----------------
__global__ __launch_bounds__(256)
void tn_k(const float* __restrict__ xb, u16* __restrict__ xt,
          float* __restrict__ ps, float* __restrict__ pq)
{
    const int bz = blockIdx.z;
    xb += (long)bz*192*HW; xt += (long)bz*HW*192;
    ps += (long)bz*576*192; pq += (long)bz*576*192;
    __shared__ float L[64 * 196];
    long n0 = (long)blockIdx.x * 64;
    int tid = threadIdx.x;
    #pragma unroll
    for (int i = 0; i < 48; ++i) {
        int idx = tid + i*256;          // 12288 = 64n x 192c
        int n = idx & 63, c = idx >> 6;
        L[n*196 + c] = xb[(long)c*HW + n0 + n];
    }
    __syncthreads();
    if (tid < 192) {                    // per-column partials, plain stores
        float s = 0.f, q = 0.f;
        #pragma unroll 8
        for (int n = 0; n < 64; ++n) { float f = L[n*196 + tid]; s += f; q = fmaf(f, f, q); }
        ps[blockIdx.x*192 + tid] = s;
        pq[blockIdx.x*192 + tid] = q;
    }
    #pragma unroll
    for (int i = 0; i < 6; ++i) {
        int idx = tid + i*256;          // 1536 = 64n x 24oct
        int oc = idx % 24, n = idx / 24;
        ushort8 v;
        #pragma unroll
        for (int e = 0; e < 8; ++e) v[e] = f2b(L[n*196 + oc*8 + e]);
        *reinterpret_cast<ushort8*>(xt + (n0+n)*192 + oc*8) = v;
    }
}

// ---------------- reduce instnorm-1 partials: one block per column ----------------
__global__ __launch_bounds__(64)
void fin1b_k(const float* __restrict__ ps, const float* __restrict__ pq, float4* __restrict__ st)
{
    int c = blockIdx.x, t = threadIdx.x, bz = blockIdx.y;
    ps += (long)bz*576*192; pq += (long)bz*576*192; st += (long)bz*192;
    float s = 0.f, q = 0.f;
    for (int b = t; b < 576; b += 64) { s += ps[b*192 + c]; q += pq[b*192 + c]; }
    for (int off = 32; off; off >>= 1) { s += __shfl_down(s, off); q += __shfl_down(q, off); }
    if (t == 0) {
        float mean = s / (float)HW;
        float var  = q / (float)HW - mean*mean;
        st[c] = make_float4(mean, rsqrtf(var + 1e-5f), 0.f, 0.f);
    }
}

// ---------------- reduce x2 stat partials ----------------
__global__ __launch_bounds__(64)
void fin2b_k(const float* __restrict__ ps, const float* __restrict__ pq,
             float* __restrict__ m, float* __restrict__ r)
{
    int c = blockIdx.x, t = threadIdx.x, bz = blockIdx.y;
    ps += (long)bz*288*192; pq += (long)bz*288*192; m += (long)bz*192; r += (long)bz*192;
    float s = 0.f, q = 0.f;
    for (int b = t; b < 288; b += 64) { s += ps[b*192 + c]; q += pq[b*192 + c]; }
    for (int off = 32; off; off >>= 1) { s += __shfl_down(s, off); q += __shfl_down(q, off); }
    if (t == 0) {
        float mean = s / (float)HW;
        float var  = q / (float)HW - mean*mean;
        m[c] = mean;
        r[c] = rsqrtf(var + 1e-5f);
    }
}

// ---------------- MFMA GEMM: out[n][m] = sum_k B[n][k] * W[m][k] ----------------
// OUTT: 0 = bf16 [n][m]; 1 = f32 [m][n] (BM=64); 2 = bf16 [m][n] planar (BM=128)
// RESID==1 additionally emits per-block x2 column-stat partials (no atomics)
template<int BM, int RESID, int OUTT>
__global__ __launch_bounds__(256)
void gemm_k(const u16* __restrict__ W, int Kpad, int K64, long wstr,
            const u16* __restrict__ B, int brs, long bstr,
            const float* __restrict__ bias, int biasstr,
            const u16* __restrict__ Rs, long rstr,
            u16* __restrict__ outA, int ors, long ostr, int Mout,
            float* __restrict__ outT, long otstr,
            float* __restrict__ p2s, float* __restrict__ p2q)
{
    constexpr int MR  = BM / 64;
    constexpr int OLS = (OUTT==0) ? (BM+8) : 130;
    constexpr int L_MAIN = 8192 + BM*64;
    constexpr int L_OUT  = (OUTT==0) ? 128*OLS : BM*130;
    constexpr int LDSU = L_MAIN > L_OUT ? L_MAIN : L_OUT;
    __shared__ u16 lds[LDSU];
    __shared__ float cws[256], cwq[256];
    u16* Xl = lds;              // [128][64] swizzled
    u16* Wl = lds + 8192;       // [BM][64]  swizzled

    const int bz = blockIdx.z;
    W += (long)bz*wstr; B += (long)bz*bstr; bias += (long)bz*biasstr;
    if (RESID) Rs += (long)bz*rstr;
    if (OUTT==1) outT += (long)bz*otstr; else outA += (long)bz*ostr;

    const int tid = threadIdx.x;
    const int m0 = blockIdx.x * BM;
    const long nn0 = (long)blockIdx.y * 128;
    const int ln = tid & 63, wv = tid >> 6;
    const int wn = (wv >> 1) * 64;
    const int wm = (wv & 1) * (BM/2);
    const int l31 = ln & 31, l5 = ln >> 5;

    const u16* Bb = B + nn0*(long)brs;
    const u16* Wb = W + (long)m0*Kpad;

    f32x16 acc[2][MR];
    #pragma unroll
    for (int a = 0; a < 2; ++a)
        #pragma unroll
        for (int b = 0; b < MR; ++b)
            #pragma unroll
            for (int r = 0; r < 16; ++r) acc[a][b][r] = 0.f;

    for (int ks = 0; ks < K64; ++ks) {
        #pragma unroll
        for (int i = 0; i < 4; ++i) {
            int chunk = i*256 + tid;
            int row = chunk >> 3, o = chunk & 7;
            int op = o ^ ((row >> 1) & 7);
            gll16(Bb + (long)row*brs + ks*64 + op*8, Xl + chunk*8);
        }
        #pragma unroll
        for (int i = 0; i < BM/32; ++i) {
            int chunk = i*256 + tid;
            int row = chunk >> 3, o = chunk & 7;
            int op = o ^ ((row >> 1) & 7);
            gll16(Wb + (long)row*Kpad + ks*64 + op*8, Wl + chunk*8);
        }
        __syncthreads();
        #pragma unroll
        for (int k16 = 0; k16 < 4; ++k16) {
            short8 af[2];
            #pragma unroll
            for (int nr = 0; nr < 2; ++nr) {
                int row = wn + nr*32 + l31;
                int slot = (k16*2 + l5) ^ ((row >> 1) & 7);
                af[nr] = *reinterpret_cast<const short8*>(&Xl[row*64 + slot*8]);
            }
            short8 bf[MR];
            #pragma unroll
            for (int mr = 0; mr < MR; ++mr) {
                int rowm = wm + mr*32 + l31;
                int slot = (k16*2 + l5) ^ ((rowm >> 1) & 7);
                bf[mr] = *reinterpret_cast<const short8*>(&Wl[rowm*64 + slot*8]);
            }
            #pragma unroll
            for (int nr = 0; nr < 2; ++nr)
                #pragma unroll
                for (int mr = 0; mr < MR; ++mr)
                    acc[nr][mr] = __builtin_amdgcn_mfma_f32_32x32x16_bf16(af[nr], bf[mr], acc[nr][mr], 0, 0, 0);
        }
        __syncthreads();
    }
    float bsv[MR];
    #pragma unroll
    for (int mr = 0; mr < MR; ++mr)
        bsv[mr] = bias[m0 + wm + mr*32 + l31];
    u16* Ol = lds;
    #pragma unroll
    for (int nr = 0; nr < 2; ++nr)
        #pragma unroll
        for (int mr = 0; mr < MR; ++mr)
            #pragma unroll
            for (int reg = 0; reg < 16; ++reg) {
                int r32 = (reg & 3) + 8*(reg >> 2) + 4*l5;
                int grow = wn + nr*32 + r32;
                int gcol = wm + mr*32 + l31;
                float val = acc[nr][mr][reg] + bsv[mr];
                if (RESID == 2)
                    val += b2f(Rs[(nn0 + grow)*192 + m0 + gcol]);
                if (OUTT == 0) Ol[grow*OLS + gcol] = f2b(val);
                else           Ol[gcol*130 + grow] = f2b(val);
            }
    __syncthreads();
    if (OUTT == 0) {
        constexpr int SPR = BM/8;
        float ls[8] = {0,0,0,0,0,0,0,0}, lq[8] = {0,0,0,0,0,0,0,0};
        #pragma unroll
        for (int i = 0; i < 128*SPR/256; ++i) {
            int idx = tid + i*256;
            int row = idx / SPR, sl = idx % SPR;
            if (m0 + sl*8 >= Mout) continue;
            ushort8 v = *reinterpret_cast<const ushort8*>(&Ol[row*OLS + sl*8]);
            if (RESID == 1) {
                ushort8 rv = *reinterpret_cast<const ushort8*>(Rs + (nn0+row)*(long)ors + m0 + sl*8);
                #pragma unroll
                for (int e = 0; e < 8; ++e) {
                    v[e] = f2b(b2f(v[e]) + b2f(rv[e]));
                    float vv = b2f(v[e]);
                    ls[e] += vv; lq[e] = fmaf(vv, vv, lq[e]);
                }
            }
            *reinterpret_cast<ushort8*>(outA + (nn0+row)*(long)ors + m0 + sl*8) = v;
        }
        if (RESID == 1) {
            #pragma unroll
            for (int e = 0; e < 8; ++e) {
                float s = ls[e], q = lq[e];
                s += __shfl_xor(s, 8);  q += __shfl_xor(q, 8);
                s += __shfl_xor(s, 16); q += __shfl_xor(q, 16);
                s += __shfl_xor(s, 32); q += __shfl_xor(q, 32);
                if (ln < 8) { cws[wv*64 + ln*8 + e] = s; cwq[wv*64 + ln*8 + e] = q; }
            }
            __syncthreads();
            if (tid < 64) {
                float s = cws[tid] + cws[64+tid] + cws[128+tid] + cws[192+tid];
                float q = cwq[tid] + cwq[64+tid] + cwq[128+tid] + cwq[192+tid];
                p2s[(long)bz*288*192 + blockIdx.y*192 + m0 + tid] = s;
                p2q[(long)bz*288*192 + blockIdx.y*192 + m0 + tid] = q;
            }
        }
    } else if (OUTT == 1) {
        // f32 transposed out (BM=64): full-row chunk mapping — 32 lanes cover one
        // 512B row contiguously per instruction (no partial-line RMW).
        #pragma unroll
        for (int pass = 0; pass < 8; ++pass) {
            int idx = pass*256 + tid;
            int row = idx >> 5, ch = idx & 31;      // 64 rows x 32 float4-chunks
            ushort4 v = *reinterpret_cast<const ushort4*>(&Ol[row*130 + ch*4]);
            float4 o = make_float4(b2f(v.x), b2f(v.y), b2f(v.z), b2f(v.w));
            *reinterpret_cast<float4*>(outT + (long)(m0 + row)*HW + nn0 + ch*4) = o;
        }
    } else {
        // bf16 planar out (BM=128): 16 lanes cover one 256B row contiguously.
        #pragma unroll
        for (int pass = 0; pass < 8; ++pass) {
            int idx = pass*256 + tid;
            int row = idx >> 4, ch = idx & 15;      // 128 rows x 16 ushort8-chunks
            if (m0 + row < Mout)
                *reinterpret_cast<ushort8*>(outA + (long)(m0 + row)*HW + nn0 + ch*8) =
                    *reinterpret_cast<const ushort8*>(&Ol[row*130 + ch*8]);
        }
    }
}

// ---------------- dwq: planar depthwise 3x3 on q/k planes + fused sumsq ----------------
__global__ __launch_bounds__(256)
void dwq_k(const u16* __restrict__ t1P, const float* __restrict__ dww,
           const float* __restrict__ dwb, u16* __restrict__ qkP,
           float* __restrict__ nacc, const u16* __restrict__ zp)
{
    const int bz = blockIdx.z;
    t1P += (long)bz*HW*576; qkP += (long)bz*384*(long)HW; nacc += (long)bz*384;
    const int plane = blockIdx.y;          // 0..383 (q then k channels)
    const int y0 = blockIdx.x * 16;
    __shared__ u16 Ts[18*192];             // 6912 B, full-width rows + y halo
    __shared__ float wq[10];
    __shared__ float wsum[4];
    const int tid = threadIdx.x;
    if (tid < 9) wq[tid] = dww[plane*9 + tid];
    if (tid == 9) wq[9] = dwb[plane];
    const u16* pl = t1P + (long)plane*HW;
    for (int i = tid; i < 432; i += 256) {     // 18 rows x 24 chunks
        int r = i / 24, c8 = i - r*24;
        int gy = y0 - 1 + r;
        const u16* src = ((unsigned)gy < 192u) ? pl + gy*192 + c8*8 : zp;
        gll16(src, Ts + i*8);
    }
    __syncthreads();
    float w[9];
    #pragma unroll
    for (int j = 0; j < 9; ++j) w[j] = wq[j];
    const float bias = wq[9];
    float sq = 0.f;
    for (int cc = tid; cc < 384; cc += 256) {  // 16 rows x 24 chunks of 8 px
        int y = cc / 24, x8 = cc - y*24;
        float a[8];
        #pragma unroll
        for (int e = 0; e < 8; ++e) a[e] = bias;
        #pragma unroll
        for (int dy = 0; dy < 3; ++dy) {
            const u16* R = &Ts[(y+dy)*192];
            ushort8 mid = *reinterpret_cast<const ushort8*>(&R[x8*8]);
            ushort8 lft = x8       ? *reinterpret_cast<const ushort8*>(&R[x8*8-8]) : (ushort8)0;
            ushort8 rgt = (x8<23)  ? *reinterpret_cast<const ushort8*>(&R[x8*8+8]) : (ushort8)0;
            float v[10];
            v[0] = b2f(lft[7]);
            #pragma unroll
            for (int e = 0; e < 8; ++e) v[1+e] = b2f(mid[e]);
            v[9] = b2f(rgt[0]);
            #pragma unroll
            for (int dx = 0; dx < 3; ++dx)
                #pragma unroll
                for (int e = 0; e < 8; ++e)
                    a[e] = fmaf(v[e+dx], w[dy*3+dx], a[e]);
        }
        ushort8 ov;
        #pragma unroll
        for (int e = 0; e < 8; ++e) { ov[e] = f2b(a[e]); sq = fmaf(a[e], a[e], sq); }
        *reinterpret_cast<ushort8*>(qkP + (long)plane*HW + (y0+y)*192 + x8*8) = ov;
    }
    for (int off = 32; off; off >>= 1) sq += __shfl_down(sq, off);
    if ((tid & 63) == 0) wsum[tid >> 6] = sq;
    __syncthreads();
    if (tid == 0) atomicAdd(&nacc[plane], wsum[0]+wsum[1]+wsum[2]+wsum[3]);
}

// ---------------- dwv: planar depthwise 3x3 on v planes + transpose to vbuf[n][192] ----------------
__global__ __launch_bounds__(256)
void dwv_k(const u16* __restrict__ t1P, const float* __restrict__ dww,
           const float* __restrict__ dwb, u16* __restrict__ vbuf,
           const u16* __restrict__ zp)
{
    const int bz = blockIdx.z;
    t1P += (long)bz*HW*576; vbuf += (long)bz*HW*192;
    const int cg = blockIdx.y;                 // 0..23, 8 v-channels each
    const int ty = blockIdx.x / 6, tx = blockIdx.x % 6;
    const int y0 = ty*8, x0 = tx*32;
    __shared__ u16 Tv[8*10*48];                // 7680 B: 8 ch x 10 rows x 48 px (x-halo'd)
    __shared__ u16 T2[256*8];                  // 4096 B transpose buffer
    __shared__ float wl[8][9];
    __shared__ float bl[8];
    const int tid = threadIdx.x;
    for (int i = tid; i < 72; i += 256) wl[i/9][i%9] = dww[(long)(384 + cg*8 + i/9)*9 + i%9];
    if (tid < 8) bl[tid] = dwb[384 + cg*8 + tid];
    for (int i = tid; i < 480; i += 256) {     // 8 ch x 10 rows x 6 chunks
        int o = i / 60; int rem = i - o*60;
        int r = rem / 6, c8 = rem - r*6;
        int gy = y0 - 1 + r;
        int gx0 = x0 - 8 + c8*8;
        const u16* src = ((unsigned)gy < 192u && (unsigned)gx0 <= 184u)
            ? t1P + (long)(384 + cg*8 + o)*HW + gy*192 + gx0 : zp;
        gll16(src, Tv + i*8);
    }
    __syncthreads();
    const int o = tid >> 5, xc = tid & 31;
    float w[9];
    #pragma unroll
    for (int j = 0; j < 9; ++j) w[j] = wl[o][j];
    const float bias = bl[o];
    const u16* base = &Tv[o*480];              // [10][48]
    #pragma unroll
    for (int y = 0; y < 8; ++y) {
        float a = bias;
        #pragma unroll
        for (int dy = 0; dy < 3; ++dy) {
            const u16* R = base + (y+dy)*48 + xc + 7;  // local col xc+dx+7
            a = fmaf(b2f(R[0]), w[dy*3+0], a);
            a = fmaf(b2f(R[1]), w[dy*3+1], a);
            a = fmaf(b2f(R[2]), w[dy*3+2], a);
        }
        T2[(y*32 + xc)*8 + o] = f2b(a);
    }
    __syncthreads();
    const int px = tid;
    const int yy = px >> 5, xx = px & 31;
    *reinterpret_cast<ushort8*>(vbuf + ((long)(y0+yy)*192 + x0+xx)*192 + cg*8) =
        *reinterpret_cast<const ushort8*>(&T2[px*8]);
}

// ---------------- MFMA attention scores: apart[ns][h][c*48+d] = sum_n q·k over n-chunk ----------------
__global__ __launch_bounds__(256)
void attnscore_k(const u16* __restrict__ qkT, float* __restrict__ apart)
{
    const int bz = blockIdx.z;
    qkT += (long)bz*384*HW; apart += (long)bz*72*9216;
    __shared__ u16 lds[8192];           // A[64][64] + B[64][64] swizzled
    u16* Al = lds;
    u16* Bl = lds + 4096;
    const int tid = threadIdx.x;
    const int h = blockIdx.y;
    const long nb = (long)blockIdx.x * 512;
    const int ln = tid & 63, wv = tid >> 6;
    const int wq = (wv >> 1) * 32, wd = (wv & 1) * 32;
    const int l31 = ln & 31, l5 = ln >> 5;

    f32x16 acc;
    #pragma unroll
    for (int r = 0; r < 16; ++r) acc[r] = 0.f;

    for (int ks = 0; ks < 8; ++ks) {
        #pragma unroll
        for (int i = 0; i < 2; ++i) {
            int chunk = i*256 + tid;
            int row = chunk >> 3, o = chunk & 7;
            int op = o ^ ((row >> 1) & 7);
            int qr = h*48 + (row < 48 ? row : 0);
            gll16(qkT + (long)qr*HW + nb + ks*64 + op*8, Al + chunk*8);
        }
        #pragma unroll
        for (int i = 0; i < 2; ++i) {
            int chunk = i*256 + tid;
            int row = chunk >> 3, o = chunk & 7;
            int op = o ^ ((row >> 1) & 7);
            int kr = 192 + h*48 + (row < 48 ? row : 0);
            gll16(qkT + (long)kr*HW + nb + ks*64 + op*8, Bl + chunk*8);
        }
        __syncthreads();
        #pragma unroll
        for (int k16 = 0; k16 < 4; ++k16) {
            int rq = wq + l31;
            int sq_ = (k16*2 + l5) ^ ((rq >> 1) & 7);
            short8 af = *reinterpret_cast<const short8*>(&Al[rq*64 + sq_*8]);
            int rk = wd + l31;
            int sk = (k16*2 + l5) ^ ((rk >> 1) & 7);
            short8 bf = *reinterpret_cast<const short8*>(&Bl[rk*64 + sk*8]);
            acc = __builtin_amdgcn_mfma_f32_32x32x16_bf16(af, bf, acc, 0, 0, 0);
        }
        __syncthreads();
    }
    float* ap = apart + ((long)blockIdx.x*4 + h) * 2304;
    #pragma unroll
    for (int reg = 0; reg < 16; ++reg) {
        int c = wq + (reg & 3) + 8*(reg >> 2) + 4*l5;
        int d = wd + l31;
        if (c < 48 && d < 48) ap[c*48 + d] = acc[reg];
    }
}

// ---------------- reduce split-n partials ----------------
__global__ __launch_bounds__(256)
void red_k(const float* __restrict__ apart, float* __restrict__ araw)
{
    const int bz = blockIdx.y;
    apart += (long)bz*72*9216; araw += (long)bz*9216;
    int idx = blockIdx.x*256 + threadIdx.x;   // 9216
    float s = 0.f;
    for (int p = 0; p < 72; ++p) s += apart[(long)p*9216 + idx];
    araw[idx] = s;
}

// ---------------- softmax (all heads, register rows) -> ssm f32 ----------------
__global__ __launch_bounds__(256)
void softmax_sm_k(const float* __restrict__ araw, const float* __restrict__ nacc,
                  const float* __restrict__ temp, float* __restrict__ ssm)
{
    const int bz = blockIdx.x;
    araw += (long)bz*9216; nacc += (long)bz*384; ssm += (long)bz*9216;
    int tid = threadIdx.x;
    if (tid >= 192) return;
    int h = tid / 48, c = tid % 48;
    float qn = fmaxf(sqrtf(nacc[h*48 + c]), 1e-12f);
    float ti = temp[h] / qn;
    const float* ar = araw + h*2304 + c*48;
    const float* nk = nacc + 192 + h*48;
    float row[48];
    float mx = -1e30f;
    #pragma unroll
    for (int d = 0; d < 48; ++d) {
        float kn = fmaxf(sqrtf(nk[d]), 1e-12f);
        row[d] = ar[d] * ti / kn;
        mx = fmaxf(mx, row[d]);
    }
    float ssum = 0.f;
    #pragma unroll
    for (int d = 0; d < 48; ++d) { float e = expf(row[d] - mx); row[d] = e; ssum += e; }
    float inv = 1.f / ssum;
    float* so = ssm + h*2304 + c*48;
    #pragma unroll
    for (int d = 0; d < 48; ++d) so[d] = row[d] * inv;
}

// ---------------- fold softmax into attn_out_w -> bf16 W2b [192][192] ----------------
__global__ __launch_bounds__(256)
void w2fold_k(const float* __restrict__ ssm, const float* __restrict__ aow,
              u16* __restrict__ W2b)
{
    const int bz = blockIdx.y;
    ssm += (long)bz*9216; W2b += (long)bz*36864;
    int idx = blockIdx.x*256 + threadIdx.x;    // 36864
    int o = idx / 192, col = idx % 192;
    int h = col / 48, d = col % 48;
    const float* ar = aow + (long)o*192 + h*48;
    const float* sp = ssm + h*2304 + d;
    float s = 0.f;
    #pragma unroll
    for (int c = 0; c < 48; ++c) s = fmaf(ar[c], sp[c*48], s);
    W2b[idx] = f2b(s);
}

// ---------------- gate: depthwise 3x3 pairs + GELU, gll16 staging + sliding window ----------------
__global__ __launch_bounds__(256)
void gate_k(const u16* __restrict__ t2h, const float* __restrict__ dww,
            const float* __restrict__ dwb, u16* __restrict__ g, int jbase,
            const u16* __restrict__ zp)
{
    const int bz = blockIdx.z;
    t2h += (long)bz*HW*512; g += (long)bz*HW*576;
    __shared__ u16 T[10*34*32];        // 21760 B
    __shared__ float w1l[16][9], w2l[16][9];
    __shared__ float b1l[16], b2l[16];
    const int tid = threadIdx.x;
    const int cg = blockIdx.y;                       // 0..15 -> 32 u16 cols = 16 pairs
    const int ty = blockIdx.x / 6, tx = blockIdx.x % 6;
    const int y0 = ty*8, x0 = tx*32;
    const int jb = jbase + cg*16;

    for (int i = tid; i < 144; i += 256) {
        int p = i/9, j = i%9;
        int gj = jb + p;
        bool ok = (gj < 510);
        w1l[p][j] = ok ? dww[(long)gj*9 + j] : 0.f;
        w2l[p][j] = ok ? dww[(long)(510+gj)*9 + j] : 0.f;
    }
    if (tid < 16) {
        int gj = jb + tid;
        bool ok = (gj < 510);
        b1l[tid] = ok ? dwb[gj] : 0.f;
        b2l[tid] = ok ? dwb[510+gj] : 0.f;
    }
    #pragma unroll
    for (int it = 0; it < 6; ++it) {
        int i = it*256 + tid;
        if (i < 1360) {
            int r = i / 136;
            int rem = i - r*136;
            int c = rem >> 2, o = rem & 3;
            int gy = y0 - 1 + r, gx = x0 - 1 + c;
            const u16* src = ((unsigned)gy < 192u && (unsigned)gx < 192u)
                ? t2h + ((long)gy*192 + gx)*512 + cg*32 + o*8 : zp;
            gll16(src, T + i*8);
        }
    }
    __syncthreads();

    const int o2 = tid & 3, xc = (tid >> 2) & 31, yh = tid >> 7;
    float w1r[4][9], w2r[4][9], b1r[4], b2r[4];
    #pragma unroll
    for (int p = 0; p < 4; ++p) {
        #pragma unroll
        for (int j = 0; j < 9; ++j) { w1r[p][j] = w1l[o2*4+p][j]; w2r[p][j] = w2l[o2*4+p][j]; }
        b1r[p] = b1l[o2*4+p]; b2r[p] = b2l[o2*4+p];
    }
    float a1[4][4], a2[4][4];
    #pragma unroll
    for (int yy = 0; yy < 4; ++yy)
        #pragma unroll
        for (int p = 0; p < 4; ++p) { a1[yy][p] = b1r[p]; a2[yy][p] = b2r[p]; }
    #pragma unroll
    for (int r = 0; r < 6; ++r) {
        const int rr = yh*4 + r;
        float f1[3][4], f2[3][4];
        #pragma unroll
        for (int dx = 0; dx < 3; ++dx) {
            ushort8 v = *reinterpret_cast<const ushort8*>(&T[(rr*34 + xc+dx)*32 + o2*8]);
            #pragma unroll
            for (int p = 0; p < 4; ++p) { f1[dx][p] = b2f(v[2*p]); f2[dx][p] = b2f(v[2*p+1]); }
        }
        #pragma unroll
        for (int yy = 0; yy < 4; ++yy) {
            const int dy = r - yy;
            if (dy < 0 || dy > 2) continue;
            #pragma unroll
            for (int dx = 0; dx < 3; ++dx)
                #pragma unroll
                for (int p = 0; p < 4; ++p) {
                    a1[yy][p] = fmaf(f1[dx][p], w1r[p][dy*3+dx], a1[yy][p]);
                    a2[yy][p] = fmaf(f2[dx][p], w2r[p][dy*3+dx], a2[yy][p]);
                }
        }
    }
    #pragma unroll
    for (int yy = 0; yy < 4; ++yy) {
        int y = yh*4 + yy;
        ushort4 ovv;
        ovv.x = f2b(gelu_exact(a1[yy][0]) * a2[yy][0]);
        ovv.y = f2b(gelu_exact(a1[yy][1]) * a2[yy][1]);
        ovv.z = f2b(gelu_exact(a1[yy][2]) * a2[yy][2]);
        ovv.w = f2b(gelu_exact(a1[yy][3]) * a2[yy][3]);
        *reinterpret_cast<ushort4*>(g + ((long)(y0+y)*192 + x0+xc)*512 + jb + o2*4) = ovv;
    }
}

extern "C" void kernel_launch(void* const* d_in, const int* in_sizes, int n_in,
                              void* d_out, int out_size, void* d_ws, size_t ws_size,
                              hipStream_t stream) {
    const float* x           = (const float*)d_in[0];
    const float* qkv_w       = (const float*)d_in[1];
    const float* qkv_bias    = (const float*)d_in[2];
    const float* qkv_dw_w    = (const float*)d_in[3];
    const float* qkv_dw_b    = (const float*)d_in[4];
    const float* attn_out_w  = (const float*)d_in[5];
    const float* attn_out_b  = (const float*)d_in[6];
    const float* temperature = (const float*)d_in[7];
    const float* proj_in_w   = (const float*)d_in[8];
    const float* proj_in_b   = (const float*)d_in[9];
    const float* dw_w        = (const float*)d_in[10];
    const float* dw_b        = (const float*)d_in[11];
    const float* proj_out_w  = (const float*)d_in[12];
    const float* proj_out_b  = (const float*)d_in[13];
    float* out = (float*)d_out;
    char* ws = (char*)d_ws;

    const bool batched = (ws_size >= 210000000ull);
    const long nb = batched ? 2 : 1;

    const long ASZ = (long)HW*192*2;
    const long CSZ = (long)HW*576*2;
    const long VSZ = (long)HW*192*2;
    const long QSZ = (long)384*HW*2;
    u16* A_   = (u16*)ws;
    u16* C_   = (u16*)(ws + nb*ASZ);          // t1P planar [576][HW] -> g[n][512]
    u16* vbuf = (u16*)(ws + nb*(ASZ + CSZ));
    u16* qkP  = (u16*)(ws + nb*(ASZ + CSZ + VSZ));   // [384][HW]
    u16* E_   = vbuf;                          // t2half [n][512] aliases vbuf+qkP
    char* wsm = ws + nb*(ASZ + CSZ + VSZ + QSZ);
    u16* W1p = (u16*)(wsm);
    u16* W2p = (u16*)(wsm + nb*245760);
    u16* W3p = (u16*)(wsm + nb*(245760 + 393216));
    u16* W2b = (u16*)(wsm + nb*(245760 + 393216) + 196608);
    float* b1p = (float*)(wsm + nb*(245760 + 393216 + 73728) + 196608);
    float* b2p = b1p + nb*640;
    float* S_  = b2p + nb*1024;
    float* zpadf = S_;                       // 8
    float* nacc  = S_ + 8;                   // nb*384
    float* araw  = nacc + nb*384;            // nb*9216
    float* ssm   = araw + nb*9216;           // nb*9216
    float4* st1  = (float4*)(ssm + nb*9216); // nb*192
    float* s2m   = (float*)(st1 + nb*192);
    float* s2r   = s2m + nb*192;
    float* apart = s2r + nb*192;             // nb*72*9216
    float* p1s = apart;
    float* p1q = apart + nb*110592;
    float* p2s = apart;
    float* p2q = apart + nb*55296;
    const u16* zp = (const u16*)zpadf;

    const long AE = (long)HW*192;
    const long CE = (long)HW*576;
    const long VE = (long)HW*192;
    const long EE = (long)HW*512;

    prep3_k<<<192, 256, 0, stream>>>(proj_out_w, W3p);

    if (batched) {
        zero_k<<<4, 256, 0, stream>>>(S_, 8 + 2*384);
        tn_k<<<dim3(576,1,2), 256, 0, stream>>>(x, A_, p1s, p1q);
        fin1b_k<<<dim3(192,2), 64, 0, stream>>>(p1s, p1q, st1);
        prep1_k<<<dim3(640,2), 192, 0, stream>>>(qkv_w, qkv_bias, st1, W1p, b1p);

        // G1: t1P[m][n] planar = (xt @ W1p^T + b1p)^T
        gemm_k<128,0,2><<<dim3(5,288,2), 256, 0, stream>>>(
            W1p, 192, 3, 640*192, A_, 192, AE, b1p, 640, nullptr, 0, C_, 0, CE, 576, nullptr, 0, nullptr, nullptr);
        dwq_k<<<dim3(12,384,2), 256, 0, stream>>>(C_, qkv_dw_w, qkv_dw_b, qkP, nacc, zp);
        dwv_k<<<dim3(144,24,2), 256, 0, stream>>>(C_, qkv_dw_w, qkv_dw_b, vbuf, zp);
        attnscore_k<<<dim3(72,4,2), 256, 0, stream>>>(qkP, apart);
        red_k<<<dim3(36,2), 256, 0, stream>>>(apart, araw);
        softmax_sm_k<<<2, 256, 0, stream>>>(araw, nacc, temperature, ssm);
        w2fold_k<<<dim3(144,2), 256, 0, stream>>>(ssm, attn_out_w, W2b);
        gemm_k<64,1,0><<<dim3(3,288,2), 256, 0, stream>>>(
            W2b, 192, 3, 36864, vbuf, 192, VE, attn_out_b, 0, A_, AE, A_, 192, AE, 192, nullptr, 0, p2s, p2q);

        fin2b_k<<<dim3(192,2), 64, 0, stream>>>(p2s, p2q, s2m, s2r);
        prep2_k<<<dim3(1024,2), 192, 0, stream>>>(proj_in_w, proj_in_b, s2m, s2r, W2p, b2p);

        gemm_k<128,0,0><<<dim3(4,288,2), 256, 0, stream>>>(
            W2p, 192, 3, 1024*192, A_, 192, AE, b2p, 1024, nullptr, 0, E_, 512, EE, 512, nullptr, 0, nullptr, nullptr);
        gate_k<<<dim3(144,16,2), 256, 0, stream>>>(E_, dw_w, dw_b, C_, 0, zp);
        gemm_k<128,0,0><<<dim3(4,288,2), 256, 0, stream>>>(
            W2p + (long)512*192, 192, 3, 1024*192, A_, 192, AE, b2p + 512, 1024, nullptr, 0, E_, 512, EE, 512, nullptr, 0, nullptr, nullptr);
        gate_k<<<dim3(144,16,2), 256, 0, stream>>>(E_, dw_w, dw_b, C_, 256, zp);

        gemm_k<64,2,1><<<dim3(3,288,2), 256, 0, stream>>>(
            W3p, 512, 8, 0, C_, 512, CE, proj_out_b, 0, A_, AE, nullptr, 0, 0, 192, out, (long)192*HW, nullptr, nullptr);
    } else {
        for (int b = 0; b < 2; ++b) {
            const float* xb = x + (long)b * 192 * HW;
            float* outb = out + (long)b * 192 * HW;

            zero_k<<<2, 256, 0, stream>>>(S_, 8 + 384);
            tn_k<<<dim3(576,1,1), 256, 0, stream>>>(xb, A_, p1s, p1q);
            fin1b_k<<<dim3(192,1), 64, 0, stream>>>(p1s, p1q, st1);
            prep1_k<<<dim3(640,1), 192, 0, stream>>>(qkv_w, qkv_bias, st1, W1p, b1p);

            gemm_k<128,0,2><<<dim3(5,288,1), 256, 0, stream>>>(
                W1p, 192, 3, 0, A_, 192, 0, b1p, 0, nullptr, 0, C_, 0, 0, 576, nullptr, 0, nullptr, nullptr);
            dwq_k<<<dim3(12,384,1), 256, 0, stream>>>(C_, qkv_dw_w, qkv_dw_b, qkP, nacc, zp);
            dwv_k<<<dim3(144,24,1), 256, 0, stream>>>(C_, qkv_dw_w, qkv_dw_b, vbuf, zp);
            attnscore_k<<<dim3(72,4,1), 256, 0, stream>>>(qkP, apart);
            red_k<<<dim3(36,1), 256, 0, stream>>>(apart, araw);
            softmax_sm_k<<<1, 256, 0, stream>>>(araw, nacc, temperature, ssm);
            w2fold_k<<<dim3(144,1), 256, 0, stream>>>(ssm, attn_out_w, W2b);
            gemm_k<64,1,0><<<dim3(3,288,1), 256, 0, stream>>>(
                W2b, 192, 3, 0, vbuf, 192, 0, attn_out_b, 0, A_, 0, A_, 192, 0, 192, nullptr, 0, p2s, p2q);

            fin2b_k<<<dim3(192,1), 64, 0, stream>>>(p2s, p2q, s2m, s2r);
            prep2_k<<<dim3(1024,1), 192, 0, stream>>>(proj_in_w, proj_in_b, s2m, s2r, W2p, b2p);

            gemm_k<128,0,0><<<dim3(4,288,1), 256, 0, stream>>>(
                W2p, 192, 3, 0, A_, 192, 0, b2p, 0, nullptr, 0, E_, 512, 0, 512, nullptr, 0, nullptr, nullptr);
            gate_k<<<dim3(144,16,1), 256, 0, stream>>>(E_, dw_w, dw_b, C_, 0, zp);
            gemm_k<128,0,0><<<dim3(4,288,1), 256, 0, stream>>>(
                W2p + (long)512*192, 192, 3, 0, A_, 192, 0, b2p + 512, 0, nullptr, 0, E_, 512, 0, 512, nullptr, 0, nullptr, nullptr);
            gate_k<<<dim3(144,16,1), 256, 0, stream>>>(E_, dw_w, dw_b, C_, 256, zp);

            gemm_k<64,2,1><<<dim3(3,288,1), 256, 0, stream>>>(
                W3p, 512, 8, 0, C_, 512, 0, proj_out_b, 0, A_, 0, nullptr, 0, 0, 192, outb, 0, nullptr, nullptr);
        }
    }
}